// Round 2
// baseline (437.143 us; speedup 1.0000x reference)
//
#include <hip/hip_runtime.h>
#include <hip/hip_bf16.h>

#define B_SZ   128
#define T_SZ   2048
#define ENCH   512
#define ATTN_  128
#define S_SPLIT 8
#define ROWS   64
#define CHUNK  (T_SZ / S_SPLIT)   // 256 rows per block
#define NT     (CHUNK / ROWS)     // 4 subtiles per block

typedef __attribute__((ext_vector_type(8))) short short8;
typedef __attribute__((ext_vector_type(4))) float f32x4;
typedef __attribute__((ext_vector_type(4))) unsigned short ushort4v;

__device__ __forceinline__ unsigned short f2bf_rne(float f) {
  unsigned u = __builtin_bit_cast(unsigned, f);
  u += 0x7FFFu + ((u >> 16) & 1u);          // round-to-nearest-even
  return (unsigned short)(u >> 16);
}
__device__ __forceinline__ float bf2f(unsigned short s) {
  return __builtin_bit_cast(float, ((unsigned)s) << 16);
}
__device__ __forceinline__ float fast_tanh(float x) {
  float e = __expf(2.f * x);
  return 1.f - __fdividef(2.f, e + 1.f);    // (e-1)/(e+1), saturates correctly
}

// ---- K0b: W_enc fp32 -> bf16 (row-major [128][512]) ----
__global__ void k_convert_wenc(const float* __restrict__ w,
                               unsigned short* __restrict__ o) {
  int i = blockIdx.x * 256 + threadIdx.x;
  float4 v = reinterpret_cast<const float4*>(w)[i];
  ushort4v u = { f2bf_rne(v.x), f2bf_rne(v.y), f2bf_rne(v.z), f2bf_rne(v.w) };
  reinterpret_cast<ushort4v*>(o)[i] = u;
}

// ---- K0a: dec_proj[b][a] = sum_h dec[b,h] * W_dec[a,h]  (fp32) ----
__global__ void k_decproj(const float* __restrict__ dec,
                          const float* __restrict__ wdec,
                          float* __restrict__ out) {
  __shared__ float dh[ENCH];
  int b = blockIdx.x, tid = threadIdx.x;    // 128 threads
  for (int i = tid; i < ENCH; i += 128) dh[i] = dec[b * ENCH + i];
  __syncthreads();
  const float4* wr4 = reinterpret_cast<const float4*>(wdec + tid * ENCH);
  float acc = 0.f;
  for (int h4 = 0; h4 < ENCH / 4; ++h4) {
    float4 w4 = wr4[h4];
    acc += dh[h4 * 4 + 0] * w4.x + dh[h4 * 4 + 1] * w4.y +
           dh[h4 * 4 + 2] * w4.z + dh[h4 * 4 + 3] * w4.w;
  }
  out[b * ATTN_ + tid] = acc;
}

__device__ __forceinline__ void stage_write(unsigned short* buf, int i4, float4 v) {
  int fo   = i4 * 4;
  int row  = fo >> 9;
  int colb = (fo & 511) * 2;
  ushort4v u = { f2bf_rne(v.x), f2bf_rne(v.y), f2bf_rne(v.z), f2bf_rne(v.w) };
  *reinterpret_cast<ushort4v*>(
      (char*)buf + row * 1024 + (colb ^ ((row & 7) << 4))) = u;
}

// ---- K1: fused enc_proj + tanh + scores + online-softmax context partials ----
// Double-buffered: prefetch subtile st+1 into regs while computing st from LDS.
__global__ __launch_bounds__(512, 2) void k_main(
    const float* __restrict__ enc,            // [B,T,512] fp32
    const unsigned short* __restrict__ wenc,  // [128,512] bf16
    const float* __restrict__ decproj,        // [B,128] fp32
    const float* __restrict__ vw,             // [128] fp32
    float* __restrict__ scores_raw,           // d_out+B*512: [B,T] raw scores
    float* __restrict__ ctx_part,             // [B,S,512]
    float* __restrict__ ml_part)              // [B,S,2]
{
  const int s    = blockIdx.x;
  const int b    = blockIdx.y;
  const int tid  = threadIdx.x;
  const int lane = tid & 63;
  const int wave = tid >> 6;      // 8 waves, wave owns attn cols [wave*16, +16)
  const int l15  = lane & 15;
  const int g    = lane >> 4;

  __shared__ unsigned short enc_lds[2][ROWS * ENCH]; // 2 x 64 KiB, XOR-swizzled
  __shared__ float scores_buf[2][ROWS];

  // Persistent B fragments: lane holds col=l15(+wave*16), k=g*8..g*8+7 per ks
  const int acol = wave * 16 + l15;
  short8 bfrag[16];
  {
    const unsigned short* wp = wenc + acol * ENCH;
#pragma unroll
    for (int ks = 0; ks < 16; ++ks)
      bfrag[ks] = *reinterpret_cast<const short8*>(wp + ks * 32 + g * 8);
  }
  const float vlane = vw[acol];
  const float dlane = decproj[b * ATTN_ + acol];

  float m_run = -INFINITY, l_run = 0.f, ctx = 0.f;   // thread owns h = tid

  const int t0 = s * CHUNK;
  const float* encb = enc + ((size_t)b * T_SZ + t0) * ENCH;

  // ---- prologue: stage subtile 0 ----
  float4 pf[16];
#pragma unroll
  for (int r = 0; r < 16; ++r)
    pf[r] = reinterpret_cast<const float4*>(encb)[r * 512 + tid];
  if (tid < 2 * ROWS) ((float*)scores_buf)[tid] = 0.f;
#pragma unroll
  for (int r = 0; r < 16; ++r)
    stage_write(enc_lds[0], r * 512 + tid, pf[r]);
  __syncthreads();

#pragma unroll
  for (int st = 0; st < NT; ++st) {
    const int c = st & 1;

    // ---- issue prefetch of subtile st+1 (in flight through compute) ----
    if (st + 1 < NT) {
      const float* src = encb + (size_t)(st + 1) * ROWS * ENCH;
#pragma unroll
      for (int r = 0; r < 16; ++r)
        pf[r] = reinterpret_cast<const float4*>(src)[r * 512 + tid];
    }

    // ---- MFMA: proj[row][acol] over K=512, from enc_lds[c] ----
    f32x4 acc[4];
#pragma unroll
    for (int mt = 0; mt < 4; ++mt) acc[mt] = (f32x4){0.f, 0.f, 0.f, 0.f};
#pragma unroll
    for (int ks = 0; ks < 16; ++ks) {
      int kbyte = (ks * 32 + g * 8) * 2;
#pragma unroll
      for (int mt = 0; mt < 4; ++mt) {
        int row = mt * 16 + l15;
        short8 a = *reinterpret_cast<const short8*>(
            (const char*)enc_lds[c] + row * 1024 + (kbyte ^ ((row & 7) << 4)));
        acc[mt] = __builtin_amdgcn_mfma_f32_16x16x32_bf16(a, bfrag[ks], acc[mt], 0, 0, 0);
      }
    }

    // ---- energy = tanh(proj + dec_proj)*v; reduce 16 cols -> score partials ----
    // C/D layout: col = l15, row = mt*16 + 4*g + r
#pragma unroll
    for (int mt = 0; mt < 4; ++mt) {
#pragma unroll
      for (int r = 0; r < 4; ++r) {
        float e = fast_tanh(acc[mt][r] + dlane) * vlane;
        e += __shfl_xor(e, 1);
        e += __shfl_xor(e, 2);
        e += __shfl_xor(e, 4);
        e += __shfl_xor(e, 8);
        if (l15 == 0) atomicAdd(&scores_buf[c][mt * 16 + g * 4 + r], e);
      }
    }

    // ---- write prefetched subtile into the other buffer (vmcnt waits here) ----
    if (st + 1 < NT) {
#pragma unroll
      for (int r = 0; r < 16; ++r)
        stage_write(enc_lds[1 - c], r * 512 + tid, pf[r]);
    }
    __syncthreads();   // bar1: scores visible; next-tile LDS writes visible

    // zero the other score buffer for subtile st+1 (consumed after bar2)
    if (st + 1 < NT && tid < ROWS) scores_buf[1 - c][tid] = 0.f;

    if (tid < ROWS)
      scores_raw[(size_t)b * T_SZ + t0 + st * ROWS + tid] = scores_buf[c][tid];

    // ---- online softmax update + context accumulation (lane owns h = tid) ----
    const float4* sb4 = reinterpret_cast<const float4*>(scores_buf[c]);
    float smax = -INFINITY;
#pragma unroll
    for (int t4 = 0; t4 < 16; ++t4) {
      float4 s4 = sb4[t4];
      smax = fmaxf(fmaxf(fmaxf(smax, s4.x), s4.y), fmaxf(s4.z, s4.w));
    }
    float m_new = fmaxf(m_run, smax);
    float scale = __expf(m_run - m_new);   // exp(-inf)=0 on first subtile
    l_run *= scale;
    ctx   *= scale;
#pragma unroll
    for (int t4 = 0; t4 < 16; ++t4) {
      float4 s4 = sb4[t4];
      float p0 = __expf(s4.x - m_new);
      float p1 = __expf(s4.y - m_new);
      float p2 = __expf(s4.z - m_new);
      float p3 = __expf(s4.w - m_new);
      l_run += (p0 + p1) + (p2 + p3);
      const char* base = (const char*)enc_lds[c];
      int t = t4 * 4;
      float e0 = bf2f(*reinterpret_cast<const unsigned short*>(
          base + (t + 0) * 1024 + ((tid * 2) ^ (((t + 0) & 7) << 4))));
      float e1 = bf2f(*reinterpret_cast<const unsigned short*>(
          base + (t + 1) * 1024 + ((tid * 2) ^ (((t + 1) & 7) << 4))));
      float e2 = bf2f(*reinterpret_cast<const unsigned short*>(
          base + (t + 2) * 1024 + ((tid * 2) ^ (((t + 2) & 7) << 4))));
      float e3 = bf2f(*reinterpret_cast<const unsigned short*>(
          base + (t + 3) * 1024 + ((tid * 2) ^ (((t + 3) & 7) << 4))));
      ctx += p0 * e0 + p1 * e1 + p2 * e2 + p3 * e3;
    }
    m_run = m_new;
    __syncthreads();   // bar2: ctx reads of enc_lds[c] done before st+1 overwrites
  }

  ctx_part[((size_t)b * S_SPLIT + s) * ENCH + tid] = ctx;
  if (tid == 0) {
    ml_part[((size_t)b * S_SPLIT + s) * 2 + 0] = m_run;
    ml_part[((size_t)b * S_SPLIT + s) * 2 + 1] = l_run;
  }
}

// ---- K2: merge splits, write context, normalize weights in place ----
__global__ void k_combine(const float* __restrict__ ctx_part,
                          const float* __restrict__ ml_part,
                          float* __restrict__ out_ctx,   // [B,512]
                          float* __restrict__ weights)   // [B,T], holds raw scores
{
  __shared__ float fac[S_SPLIT];
  __shared__ float Msh, Lsh;
  int b = blockIdx.x, tid = threadIdx.x;   // 256 threads
  if (tid == 0) {
    float M = -INFINITY;
    for (int s2 = 0; s2 < S_SPLIT; ++s2)
      M = fmaxf(M, ml_part[(b * S_SPLIT + s2) * 2]);
    float L = 0.f;
    for (int s2 = 0; s2 < S_SPLIT; ++s2) {
      float f = __expf(ml_part[(b * S_SPLIT + s2) * 2] - M);
      fac[s2] = f;
      L += f * ml_part[(b * S_SPLIT + s2) * 2 + 1];
    }
    Msh = M; Lsh = L;
  }
  __syncthreads();
  float M = Msh, Linv = 1.f / Lsh;
  for (int h = tid; h < ENCH; h += 256) {
    float a = 0.f;
    for (int s2 = 0; s2 < S_SPLIT; ++s2)
      a += ctx_part[(b * S_SPLIT + s2) * ENCH + h] * fac[s2];
    out_ctx[b * ENCH + h] = a * Linv;
  }
  for (int t = tid; t < T_SZ; t += 256) {
    float raw = weights[(size_t)b * T_SZ + t];
    weights[(size_t)b * T_SZ + t] = __expf(raw - M) * Linv;
  }
}

extern "C" void kernel_launch(void* const* d_in, const int* in_sizes, int n_in,
                              void* d_out, int out_size, void* d_ws, size_t ws_size,
                              hipStream_t stream) {
  const float* enc  = (const float*)d_in[0];
  const float* dec  = (const float*)d_in[1];
  const float* wenc = (const float*)d_in[2];
  const float* wdec = (const float*)d_in[3];
  const float* vw   = (const float*)d_in[4];

  float* out     = (float*)d_out;
  float* out_ctx = out;                       // [B,512]
  float* out_w   = out + B_SZ * ENCH;         // [B,T] (raw scores, then weights)

  char* ws = (char*)d_ws;
  unsigned short* wenc_bf = (unsigned short*)ws;                    // 131072 B
  float* decproj  = (float*)(ws + 131072);                          // 65536 B
  float* ml_part  = (float*)(ws + 131072 + 65536);                  // 8192 B
  float* ctx_part = (float*)(ws + 131072 + 65536 + 8192);           // 2 MiB

  hipLaunchKernelGGL(k_convert_wenc, dim3(64), dim3(256), 0, stream, wenc, wenc_bf);
  hipLaunchKernelGGL(k_decproj, dim3(B_SZ), dim3(128), 0, stream, dec, wdec, decproj);
  hipLaunchKernelGGL(k_main, dim3(S_SPLIT, B_SZ), dim3(512), 0, stream,
                     enc, wenc_bf, decproj, vw, out_w, ctx_part, ml_part);
  hipLaunchKernelGGL(k_combine, dim3(B_SZ), dim3(256), 0, stream,
                     ctx_part, ml_part, out_ctx, out_w);
}

// Round 3
// 245.590 us; speedup vs baseline: 1.7800x; 1.7800x over previous
//
#include <hip/hip_runtime.h>
#include <hip/hip_bf16.h>

#define B_SZ   128
#define T_SZ   2048
#define ENCH   512
#define ATTN_  128
#define S_SPLIT 8
#define ROWS   32
#define CHUNK  (T_SZ / S_SPLIT)   // 256 rows per block
#define NT     (CHUNK / ROWS)     // 8 subtiles per block

typedef __attribute__((ext_vector_type(8))) short short8;
typedef __attribute__((ext_vector_type(4))) float f32x4;
typedef __attribute__((ext_vector_type(4))) unsigned short ushort4v;

__device__ __forceinline__ unsigned short f2bf_rne(float f) {
  unsigned u = __builtin_bit_cast(unsigned, f);
  u += 0x7FFFu + ((u >> 16) & 1u);          // round-to-nearest-even
  return (unsigned short)(u >> 16);
}
__device__ __forceinline__ float bf2f(unsigned short s) {
  return __builtin_bit_cast(float, ((unsigned)s) << 16);
}
__device__ __forceinline__ float fast_tanh(float x) {
  float e = __expf(2.f * x);
  return 1.f - __fdividef(2.f, e + 1.f);
}

// ---- K0b: W_enc fp32 -> bf16 in FRAGMENT-LINEAR order ----
// out[((w*16+ks)*64 + l)*8 + j] = bf16(W[w*16 + (l&15)][ks*32 + (l>>4)*8 + j])
// so k_main's per-(wave,ks) bfrag load is one fully-coalesced 1 KB dwordx4.
__global__ void k_convert_wfrag(const float* __restrict__ w,
                                unsigned short* __restrict__ o) {
  int idx = blockIdx.x * 256 + threadIdx.x;   // 8192 threads
  int l   = idx & 63;
  int wks = idx >> 6;
  int wv  = wks >> 4, ks = wks & 15;
  int row = wv * 16 + (l & 15);
  int col = ks * 32 + (l >> 4) * 8;
  const float4* src = reinterpret_cast<const float4*>(w + row * ENCH + col);
  float4 v0 = src[0], v1 = src[1];
  ushort4v u0 = { f2bf_rne(v0.x), f2bf_rne(v0.y), f2bf_rne(v0.z), f2bf_rne(v0.w) };
  ushort4v u1 = { f2bf_rne(v1.x), f2bf_rne(v1.y), f2bf_rne(v1.z), f2bf_rne(v1.w) };
  ushort4v* dst = reinterpret_cast<ushort4v*>(o + (size_t)idx * 8);
  dst[0] = u0;
  dst[1] = u1;
}

// ---- K0a: dec_proj[b][a] = sum_h dec[b,h] * W_dec[a,h]  (fp32) ----
__global__ void k_decproj(const float* __restrict__ dec,
                          const float* __restrict__ wdec,
                          float* __restrict__ out) {
  __shared__ float dh[ENCH];
  int b = blockIdx.x, tid = threadIdx.x;    // 128 threads
  for (int i = tid; i < ENCH; i += 128) dh[i] = dec[b * ENCH + i];
  __syncthreads();
  const float4* wr4 = reinterpret_cast<const float4*>(wdec + tid * ENCH);
  float acc = 0.f;
  for (int h4 = 0; h4 < ENCH / 4; ++h4) {
    float4 w4 = wr4[h4];
    acc += dh[h4 * 4 + 0] * w4.x + dh[h4 * 4 + 1] * w4.y +
           dh[h4 * 4 + 2] * w4.z + dh[h4 * 4 + 3] * w4.w;
  }
  out[b * ATTN_ + tid] = acc;
}

// ---- K1: fused enc_proj + tanh + scores + online-softmax context partials ----
// Occupancy-first: 32-row tile (32 KiB LDS), W streamed from L2 per k-step,
// target VGPR<=64 -> 8 waves/SIMD -> 4 blocks/CU; overlap via TLP.
__global__ __launch_bounds__(512, 8) void k_main(
    const float* __restrict__ enc,            // [B,T,512] fp32
    const unsigned short* __restrict__ wfrag, // fragment-linear bf16 W_enc
    const float* __restrict__ decproj,        // [B,128] fp32
    const float* __restrict__ vw,             // [128] fp32
    float* __restrict__ scores_raw,           // [B,T] raw scores (d_out tail)
    float* __restrict__ ctx_part,             // [B,S,512]
    float* __restrict__ ml_part)              // [B,S,2]
{
  const int s    = blockIdx.x;
  const int b    = blockIdx.y;
  const int tid  = threadIdx.x;
  const int lane = tid & 63;
  const int wave = tid >> 6;      // 8 waves, wave owns attn cols [wave*16, +16)
  const int l15  = lane & 15;
  const int g    = lane >> 4;

  __shared__ unsigned short enc_lds[ROWS * ENCH]; // 32 KiB, XOR-swizzled rows
  __shared__ float scores_buf[ROWS];

  const int acol = wave * 16 + l15;
  const float vlane = vw[acol];
  const float dlane = decproj[b * ATTN_ + acol];
  // per-(wave,lane) base into fragment-linear W; stride per ks = 512 shorts
  const unsigned short* wf = wfrag + ((size_t)(wave * 16) * 64 + lane) * 8;

  float m_run = -INFINITY, l_run = 0.f, ctx = 0.f;   // thread owns h = tid

  const float* encb = enc + ((size_t)b * T_SZ + s * CHUNK) * ENCH;

  for (int st = 0; st < NT; ++st) {
    __syncthreads();   // bar0: prev subtile's ctx reads done before overwrite

    // ---- stage 32x512 fp32 -> bf16 LDS, swizzle byte ^= ((row&7)<<4) ----
    const float* src = encb + (size_t)st * ROWS * ENCH;
#pragma unroll
    for (int r = 0; r < 8; ++r) {
      int i4 = r * 512 + tid;                 // float4 index, 4096 per subtile
      float4 v = reinterpret_cast<const float4*>(src)[i4];
      int fo   = i4 * 4;
      int row  = fo >> 9;
      int colb = (fo & 511) * 2;
      ushort4v u = { f2bf_rne(v.x), f2bf_rne(v.y), f2bf_rne(v.z), f2bf_rne(v.w) };
      *reinterpret_cast<ushort4v*>(
          (char*)enc_lds + row * 1024 + (colb ^ ((row & 7) << 4))) = u;
    }
    if (tid < ROWS) scores_buf[tid] = 0.f;
    __syncthreads();   // bar1

    // ---- MFMA: proj[row][acol] over K=512; bfrag streamed from L2 ----
    f32x4 acc0 = (f32x4){0.f, 0.f, 0.f, 0.f};
    f32x4 acc1 = (f32x4){0.f, 0.f, 0.f, 0.f};
    short8 bf_cur = *reinterpret_cast<const short8*>(wf);
    const char* base = (const char*)enc_lds;
    const int sw = (l15 & 7) << 4;            // rows l15 and l15+16 share row&7
#pragma unroll 4
    for (int ks = 0; ks < 16; ++ks) {
      short8 bf_nxt;
      if (ks < 15) bf_nxt = *reinterpret_cast<const short8*>(wf + (ks + 1) * 512);
      int kb = (ks * 32 + g * 8) * 2;
      short8 a0 = *reinterpret_cast<const short8*>(
          base + l15 * 1024 + (kb ^ sw));
      short8 a1 = *reinterpret_cast<const short8*>(
          base + (16 + l15) * 1024 + (kb ^ sw));
      acc0 = __builtin_amdgcn_mfma_f32_16x16x32_bf16(a0, bf_cur, acc0, 0, 0, 0);
      acc1 = __builtin_amdgcn_mfma_f32_16x16x32_bf16(a1, bf_cur, acc1, 0, 0, 0);
      bf_cur = bf_nxt;
    }

    // ---- energy = tanh(proj + dec)*v; reduce 16 cols -> score partials ----
    // C/D layout: col = l15, row = mt*16 + 4*g + r
#pragma unroll
    for (int r = 0; r < 4; ++r) {
      float e0 = fast_tanh(acc0[r] + dlane) * vlane;
      e0 += __shfl_xor(e0, 1);
      e0 += __shfl_xor(e0, 2);
      e0 += __shfl_xor(e0, 4);
      e0 += __shfl_xor(e0, 8);
      if (l15 == 0) atomicAdd(&scores_buf[g * 4 + r], e0);
      float e1 = fast_tanh(acc1[r] + dlane) * vlane;
      e1 += __shfl_xor(e1, 1);
      e1 += __shfl_xor(e1, 2);
      e1 += __shfl_xor(e1, 4);
      e1 += __shfl_xor(e1, 8);
      if (l15 == 0) atomicAdd(&scores_buf[16 + g * 4 + r], e1);
    }
    __syncthreads();   // bar2: scores complete

    if (tid < ROWS)
      scores_raw[(size_t)b * T_SZ + s * CHUNK + st * ROWS + tid] = scores_buf[tid];

    // ---- online softmax update + context accumulation (lane owns h = tid) ----
    const float4* sb4 = reinterpret_cast<const float4*>(scores_buf);
    float smax = -INFINITY;
#pragma unroll
    for (int t4 = 0; t4 < 8; ++t4) {
      float4 s4 = sb4[t4];
      smax = fmaxf(fmaxf(fmaxf(smax, s4.x), s4.y), fmaxf(s4.z, s4.w));
    }
    float m_new = fmaxf(m_run, smax);
    float scale = __expf(m_run - m_new);   // exp(-inf)=0 on first subtile
    l_run *= scale;
    ctx   *= scale;
#pragma unroll
    for (int t4 = 0; t4 < 8; ++t4) {
      float4 s4 = sb4[t4];
      float p0 = __expf(s4.x - m_new);
      float p1 = __expf(s4.y - m_new);
      float p2 = __expf(s4.z - m_new);
      float p3 = __expf(s4.w - m_new);
      l_run += (p0 + p1) + (p2 + p3);
      int t = t4 * 4;
      float e0 = bf2f(*reinterpret_cast<const unsigned short*>(
          base + (t + 0) * 1024 + ((tid * 2) ^ (((t + 0) & 7) << 4))));
      float e1 = bf2f(*reinterpret_cast<const unsigned short*>(
          base + (t + 1) * 1024 + ((tid * 2) ^ (((t + 1) & 7) << 4))));
      float e2 = bf2f(*reinterpret_cast<const unsigned short*>(
          base + (t + 2) * 1024 + ((tid * 2) ^ (((t + 2) & 7) << 4))));
      float e3 = bf2f(*reinterpret_cast<const unsigned short*>(
          base + (t + 3) * 1024 + ((tid * 2) ^ (((t + 3) & 7) << 4))));
      ctx += p0 * e0 + p1 * e1 + p2 * e2 + p3 * e3;
    }
    m_run = m_new;
  }

  ctx_part[((size_t)b * S_SPLIT + s) * ENCH + tid] = ctx;
  if (tid == 0) {
    ml_part[((size_t)b * S_SPLIT + s) * 2 + 0] = m_run;
    ml_part[((size_t)b * S_SPLIT + s) * 2 + 1] = l_run;
  }
}

// ---- K2: merge splits, write context, normalize weights in place ----
__global__ void k_combine(const float* __restrict__ ctx_part,
                          const float* __restrict__ ml_part,
                          float* __restrict__ out_ctx,   // [B,512]
                          float* __restrict__ weights)   // [B,T], holds raw scores
{
  __shared__ float fac[S_SPLIT];
  __shared__ float Msh, Lsh;
  int b = blockIdx.x, tid = threadIdx.x;   // 256 threads
  if (tid == 0) {
    float M = -INFINITY;
    for (int s2 = 0; s2 < S_SPLIT; ++s2)
      M = fmaxf(M, ml_part[(b * S_SPLIT + s2) * 2]);
    float L = 0.f;
    for (int s2 = 0; s2 < S_SPLIT; ++s2) {
      float f = __expf(ml_part[(b * S_SPLIT + s2) * 2] - M);
      fac[s2] = f;
      L += f * ml_part[(b * S_SPLIT + s2) * 2 + 1];
    }
    Msh = M; Lsh = L;
  }
  __syncthreads();
  float M = Msh, Linv = 1.f / Lsh;
  for (int h = tid; h < ENCH; h += 256) {
    float a = 0.f;
    for (int s2 = 0; s2 < S_SPLIT; ++s2)
      a += ctx_part[(b * S_SPLIT + s2) * ENCH + h] * fac[s2];
    out_ctx[b * ENCH + h] = a * Linv;
  }
  for (int t = tid; t < T_SZ; t += 256) {
    float raw = weights[(size_t)b * T_SZ + t];
    weights[(size_t)b * T_SZ + t] = __expf(raw - M) * Linv;
  }
}

extern "C" void kernel_launch(void* const* d_in, const int* in_sizes, int n_in,
                              void* d_out, int out_size, void* d_ws, size_t ws_size,
                              hipStream_t stream) {
  const float* enc  = (const float*)d_in[0];
  const float* dec  = (const float*)d_in[1];
  const float* wenc = (const float*)d_in[2];
  const float* wdec = (const float*)d_in[3];
  const float* vw   = (const float*)d_in[4];

  float* out     = (float*)d_out;
  float* out_ctx = out;                       // [B,512]
  float* out_w   = out + B_SZ * ENCH;         // [B,T] (raw scores, then weights)

  char* ws = (char*)d_ws;
  unsigned short* wfrag = (unsigned short*)ws;                      // 131072 B
  float* decproj  = (float*)(ws + 131072);                          // 65536 B
  float* ml_part  = (float*)(ws + 131072 + 65536);                  // 8192 B
  float* ctx_part = (float*)(ws + 131072 + 65536 + 8192);           // 2 MiB

  hipLaunchKernelGGL(k_convert_wfrag, dim3(32), dim3(256), 0, stream, wenc, wfrag);
  hipLaunchKernelGGL(k_decproj, dim3(B_SZ), dim3(128), 0, stream, dec, wdec, decproj);
  hipLaunchKernelGGL(k_main, dim3(S_SPLIT, B_SZ), dim3(512), 0, stream,
                     enc, wfrag, decproj, vw, out_w, ctx_part, ml_part);
  hipLaunchKernelGGL(k_combine, dim3(B_SZ), dim3(256), 0, stream,
                     ctx_part, ml_part, out_ctx, out_w);
}

// Round 4
// 196.569 us; speedup vs baseline: 2.2239x; 1.2494x over previous
//
#include <hip/hip_runtime.h>
#include <hip/hip_bf16.h>

#define B_SZ   128
#define T_SZ   2048
#define ENCH   512
#define ATTN_  128
#define S_SPLIT 8
#define CHUNK  (T_SZ / S_SPLIT)   // 256 rows per block = 16 waves x 16 rows

typedef __attribute__((ext_vector_type(8))) short short8;
typedef __attribute__((ext_vector_type(4))) float f32x4;
typedef __attribute__((ext_vector_type(4))) unsigned short ushort4v;

__device__ __forceinline__ unsigned short f2bf_rne(float f) {
  unsigned u = __builtin_bit_cast(unsigned, f);
  u += 0x7FFFu + ((u >> 16) & 1u);          // round-to-nearest-even
  return (unsigned short)(u >> 16);
}
__device__ __forceinline__ float fast_tanh(float x) {
  float e = __expf(2.f * x);
  return 1.f - __fdividef(2.f, e + 1.f);
}
__device__ __forceinline__ short8 pack8(float4 a, float4 b) {
  short8 r;
  r[0] = (short)f2bf_rne(a.x); r[1] = (short)f2bf_rne(a.y);
  r[2] = (short)f2bf_rne(a.z); r[3] = (short)f2bf_rne(a.w);
  r[4] = (short)f2bf_rne(b.x); r[5] = (short)f2bf_rne(b.y);
  r[6] = (short)f2bf_rne(b.z); r[7] = (short)f2bf_rne(b.w);
  return r;
}

// ---- K0b: W_enc fp32 -> bf16 in FRAGMENT-LINEAR order ----
// out[((cg*16+ks)*64 + l)*8 + j] = bf16(W[cg*16 + (l&15)][ks*32 + (l>>4)*8 + j])
__global__ void k_convert_wfrag(const float* __restrict__ w,
                                unsigned short* __restrict__ o) {
  int idx = blockIdx.x * 256 + threadIdx.x;   // 8192 threads
  int l   = idx & 63;
  int wks = idx >> 6;
  int cg  = wks >> 4, ks = wks & 15;
  int row = cg * 16 + (l & 15);
  int col = ks * 32 + (l >> 4) * 8;
  const float4* src = reinterpret_cast<const float4*>(w + row * ENCH + col);
  float4 v0 = src[0], v1 = src[1];
  *reinterpret_cast<short8*>(o + (size_t)idx * 8) = pack8(v0, v1);
}

// ---- K0a: dec_proj[b][a] = sum_h dec[b,h] * W_dec[a,h]  (fp32) ----
__global__ void k_decproj(const float* __restrict__ dec,
                          const float* __restrict__ wdec,
                          float* __restrict__ out) {
  __shared__ float dh[ENCH];
  int b = blockIdx.x, tid = threadIdx.x;    // 128 threads
  for (int i = tid; i < ENCH; i += 128) dh[i] = dec[b * ENCH + i];
  __syncthreads();
  const float4* wr4 = reinterpret_cast<const float4*>(wdec + tid * ENCH);
  float acc = 0.f;
  for (int h4 = 0; h4 < ENCH / 4; ++h4) {
    float4 w4 = wr4[h4];
    acc += dh[h4 * 4 + 0] * w4.x + dh[h4 * 4 + 1] * w4.y +
           dh[h4 * 4 + 2] * w4.z + dh[h4 * 4 + 3] * w4.w;
  }
  out[b * ATTN_ + tid] = acc;
}

// ---- K1: row-partitioned fused kernel. 16 waves, each owns 16 rows,
//      NO barriers in the hot path. W_enc lives frag-linear in LDS. ----
__global__ __launch_bounds__(1024, 4) void k_main(
    const float* __restrict__ enc,            // [B,T,512] fp32
    const unsigned short* __restrict__ wfrag, // frag-linear bf16 W_enc
    const float* __restrict__ decproj,        // [B,128] fp32
    const float* __restrict__ vw,             // [128] fp32
    float* __restrict__ scores_raw,           // [B,T] raw scores
    float* __restrict__ ctx_part,             // [B,S,512]
    float* __restrict__ ml_part)              // [B,S,2]
{
  const int s    = blockIdx.x;
  const int b    = blockIdx.y;
  const int tid  = threadIdx.x;
  const int lane = tid & 63;
  const int wid  = tid >> 6;       // 16 waves
  const int l15  = lane & 15;
  const int g    = lane >> 4;

  __shared__ unsigned short w_lds[ATTN_ * ENCH];  // 128 KiB, frag-linear
  __shared__ float p_lds[16][16];                 // per-wave raw scores
  __shared__ float ml_red[16][2];

  // ---- stage W into LDS (one time; linear copy, coalesced, conflict-free) ----
#pragma unroll
  for (int r = 0; r < 8; ++r) {
    int i = r * 1024 + tid;
    reinterpret_cast<short8*>(w_lds)[i] = reinterpret_cast<const short8*>(wfrag)[i];
  }

  // per-lane d,v for cols cg*16 + l15
  float dv[8], vv[8];
#pragma unroll
  for (int cg = 0; cg < 8; ++cg) {
    dv[cg] = decproj[b * ATTN_ + cg * 16 + l15];
    vv[cg] = vw[cg * 16 + l15];
  }
  __syncthreads();   // W visible to all waves; last barrier before hot path

  // ================= wave-private hot path (no block syncs) =================
  const int row0 = s * CHUNK + wid * 16;
  const float* arow = enc + ((size_t)b * T_SZ + row0 + l15) * ENCH + g * 8;

  f32x4 acc[8];
#pragma unroll
  for (int cg = 0; cg < 8; ++cg) acc[cg] = (f32x4){0.f, 0.f, 0.f, 0.f};

  // K loop: A from global (fp32, exact 128B/row/ks chunks), B from LDS.
  float4 a0 = *reinterpret_cast<const float4*>(arow);
  float4 a1 = *reinterpret_cast<const float4*>(arow + 4);
#pragma unroll
  for (int ks = 0; ks < 16; ++ks) {
    float4 n0, n1;
    if (ks < 15) {
      n0 = *reinterpret_cast<const float4*>(arow + (ks + 1) * 32);
      n1 = *reinterpret_cast<const float4*>(arow + (ks + 1) * 32 + 4);
    }
    short8 af = pack8(a0, a1);
    const char* wb = (const char*)w_lds + (size_t)ks * 1024 + lane * 16;
#pragma unroll
    for (int cg = 0; cg < 8; ++cg) {
      short8 bf = *reinterpret_cast<const short8*>(wb + cg * 16384);
      acc[cg] = __builtin_amdgcn_mfma_f32_16x16x32_bf16(af, bf, acc[cg], 0, 0, 0);
    }
    a0 = n0; a1 = n1;
  }

  // ---- energy = tanh(proj+dec)*v; reduce over 128 cols -> 16 row scores ----
  // C/D layout: col = cg*16 + l15, row = 4*g + r
#pragma unroll
  for (int r = 0; r < 4; ++r) {
    float e = 0.f;
#pragma unroll
    for (int cg = 0; cg < 8; ++cg)
      e += fast_tanh(acc[cg][r] + dv[cg]) * vv[cg];
    e += __shfl_xor(e, 1);
    e += __shfl_xor(e, 2);
    e += __shfl_xor(e, 4);
    e += __shfl_xor(e, 8);
    if (l15 == 0) {
      p_lds[wid][g * 4 + r] = e;
      scores_raw[(size_t)b * T_SZ + row0 + g * 4 + r] = e;
    }
  }
  // intra-wave LDS visibility: drain ds writes, block reordering
  asm volatile("s_waitcnt lgkmcnt(0)" ::: "memory");
  __builtin_amdgcn_wave_barrier();

  // ---- wave-private softmax over its 16 rows ----
  float sc16[16];
#pragma unroll
  for (int t = 0; t < 16; ++t) sc16[t] = p_lds[wid][t];   // broadcast reads
  float m = sc16[0];
#pragma unroll
  for (int t = 1; t < 16; ++t) m = fmaxf(m, sc16[t]);
  float l_run = 0.f;
#pragma unroll
  for (int t = 0; t < 16; ++t) { sc16[t] = __expf(sc16[t] - m); l_run += sc16[t]; }

  // ---- ctx partial: lane owns h = lane*8..+8; enc re-read hits L2 ----
  float ctx[8];
#pragma unroll
  for (int j = 0; j < 8; ++j) ctx[j] = 0.f;
  const float* crow = enc + ((size_t)b * T_SZ + row0) * ENCH + lane * 8;
#pragma unroll 4
  for (int t = 0; t < 16; ++t) {
    float4 e0 = *reinterpret_cast<const float4*>(crow + (size_t)t * ENCH);
    float4 e1 = *reinterpret_cast<const float4*>(crow + (size_t)t * ENCH + 4);
    float p = sc16[t];
    ctx[0] += p * e0.x; ctx[1] += p * e0.y; ctx[2] += p * e0.z; ctx[3] += p * e0.w;
    ctx[4] += p * e1.x; ctx[5] += p * e1.y; ctx[6] += p * e1.z; ctx[7] += p * e1.w;
  }

  // ================= block reduce (W-LDS reused as scratch) =================
  __syncthreads();   // all waves done reading w_lds
  float* ctx_red = reinterpret_cast<float*>(w_lds);   // [16][512]
  float4* cr4 = reinterpret_cast<float4*>(ctx_red + wid * ENCH + lane * 8);
  cr4[0] = (float4){ctx[0], ctx[1], ctx[2], ctx[3]};
  cr4[1] = (float4){ctx[4], ctx[5], ctx[6], ctx[7]};
  if (lane == 0) { ml_red[wid][0] = m; ml_red[wid][1] = l_run; }
  __syncthreads();

  if (tid < ENCH) {
    float M = ml_red[0][0];
#pragma unroll
    for (int w = 1; w < 16; ++w) M = fmaxf(M, ml_red[w][0]);
    float L = 0.f, c = 0.f;
#pragma unroll
    for (int w = 0; w < 16; ++w) {
      float f = __expf(ml_red[w][0] - M);
      L += f * ml_red[w][1];
      c += f * ctx_red[w * ENCH + tid];
    }
    ctx_part[((size_t)b * S_SPLIT + s) * ENCH + tid] = c;
    if (tid == 0) {
      ml_part[((size_t)b * S_SPLIT + s) * 2 + 0] = M;
      ml_part[((size_t)b * S_SPLIT + s) * 2 + 1] = L;
    }
  }
}

// ---- K2: merge splits, write context, normalize weights in place ----
__global__ void k_combine(const float* __restrict__ ctx_part,
                          const float* __restrict__ ml_part,
                          float* __restrict__ out_ctx,   // [B,512]
                          float* __restrict__ weights)   // [B,T], holds raw scores
{
  __shared__ float fac[S_SPLIT];
  __shared__ float Msh, Lsh;
  int b = blockIdx.x, tid = threadIdx.x;   // 256 threads
  if (tid == 0) {
    float M = -INFINITY;
    for (int s2 = 0; s2 < S_SPLIT; ++s2)
      M = fmaxf(M, ml_part[(b * S_SPLIT + s2) * 2]);
    float L = 0.f;
    for (int s2 = 0; s2 < S_SPLIT; ++s2) {
      float f = __expf(ml_part[(b * S_SPLIT + s2) * 2] - M);
      fac[s2] = f;
      L += f * ml_part[(b * S_SPLIT + s2) * 2 + 1];
    }
    Msh = M; Lsh = L;
  }
  __syncthreads();
  float M = Msh, Linv = 1.f / Lsh;
  for (int h = tid; h < ENCH; h += 256) {
    float a = 0.f;
    for (int s2 = 0; s2 < S_SPLIT; ++s2)
      a += ctx_part[(b * S_SPLIT + s2) * ENCH + h] * fac[s2];
    out_ctx[b * ENCH + h] = a * Linv;
  }
  for (int t = tid; t < T_SZ; t += 256) {
    float raw = weights[(size_t)b * T_SZ + t];
    weights[(size_t)b * T_SZ + t] = __expf(raw - M) * Linv;
  }
}

extern "C" void kernel_launch(void* const* d_in, const int* in_sizes, int n_in,
                              void* d_out, int out_size, void* d_ws, size_t ws_size,
                              hipStream_t stream) {
  const float* enc  = (const float*)d_in[0];
  const float* dec  = (const float*)d_in[1];
  const float* wenc = (const float*)d_in[2];
  const float* wdec = (const float*)d_in[3];
  const float* vw   = (const float*)d_in[4];

  float* out     = (float*)d_out;
  float* out_ctx = out;                       // [B,512]
  float* out_w   = out + B_SZ * ENCH;         // [B,T] (raw scores, then weights)

  char* ws = (char*)d_ws;
  unsigned short* wfrag = (unsigned short*)ws;                      // 131072 B
  float* decproj  = (float*)(ws + 131072);                          // 65536 B
  float* ml_part  = (float*)(ws + 131072 + 65536);                  // 8192 B
  float* ctx_part = (float*)(ws + 131072 + 65536 + 8192);           // 2 MiB

  hipLaunchKernelGGL(k_convert_wfrag, dim3(32), dim3(256), 0, stream, wenc, wfrag);
  hipLaunchKernelGGL(k_decproj, dim3(B_SZ), dim3(128), 0, stream, dec, wdec, decproj);
  hipLaunchKernelGGL(k_main, dim3(S_SPLIT, B_SZ), dim3(1024), 0, stream,
                     enc, wfrag, decproj, vw, out_w, ctx_part, ml_part);
  hipLaunchKernelGGL(k_combine, dim3(B_SZ), dim3(256), 0, stream,
                     ctx_part, ml_part, out_ctx, out_w);
}

// Round 5
// 193.088 us; speedup vs baseline: 2.2640x; 1.0180x over previous
//
#include <hip/hip_runtime.h>
#include <hip/hip_bf16.h>

#define B_SZ   128
#define T_SZ   2048
#define ENCH   512
#define ATTN_  128
#define S_SPLIT 8
#define CHUNK  (T_SZ / S_SPLIT)   // 256 rows per chunk = 16 waves x 16 rows
#define NCHUNK (S_SPLIT * B_SZ)   // 1024 logical chunks

typedef __attribute__((ext_vector_type(8))) short short8;
typedef __attribute__((ext_vector_type(4))) float f32x4;

__device__ __forceinline__ unsigned short f2bf_rne(float f) {
  unsigned u = __builtin_bit_cast(unsigned, f);
  u += 0x7FFFu + ((u >> 16) & 1u);
  return (unsigned short)(u >> 16);
}
__device__ __forceinline__ float bf2f(unsigned short s) {
  return __builtin_bit_cast(float, ((unsigned)s) << 16);
}
__device__ __forceinline__ float fast_tanh(float x) {
  float e = __expf(2.f * x);
  return 1.f - __fdividef(2.f, e + 1.f);
}
// HW packed f32->bf16 (RNE), 2 elems per instruction
__device__ __forceinline__ short8 pack8(float4 a, float4 b) {
  union { unsigned u[4]; short8 s; } r;
  asm("v_cvt_pk_bf16_f32 %0, %1, %2" : "=v"(r.u[0]) : "v"(a.x), "v"(a.y));
  asm("v_cvt_pk_bf16_f32 %0, %1, %2" : "=v"(r.u[1]) : "v"(a.z), "v"(a.w));
  asm("v_cvt_pk_bf16_f32 %0, %1, %2" : "=v"(r.u[2]) : "v"(b.x), "v"(b.y));
  asm("v_cvt_pk_bf16_f32 %0, %1, %2" : "=v"(r.u[3]) : "v"(b.z), "v"(b.w));
  return r.s;
}
// 16-lane (l15) sum via DPP: quad_perm xor1, xor2, half-mirror, mirror.
// Pure VALU - no LDS pipe. All 16 lanes of the group end with the sum.
template<int CTRL>
__device__ __forceinline__ float dpp_add(float v) {
  int t = __builtin_amdgcn_update_dpp(0, __builtin_bit_cast(int, v),
                                      CTRL, 0xf, 0xf, true);
  return v + __builtin_bit_cast(float, t);
}
__device__ __forceinline__ float sum16(float v) {
  v = dpp_add<0xB1>(v);    // quad_perm [1,0,3,2]  (xor 1)
  v = dpp_add<0x4E>(v);    // quad_perm [2,3,0,1]  (xor 2)
  v = dpp_add<0x141>(v);   // row_half_mirror      (xor 4 once quads uniform)
  v = dpp_add<0x140>(v);   // row_mirror           (xor 8 once octs uniform)
  return v;
}

// ---- K0b: W_enc fp32 -> bf16 in FRAGMENT-LINEAR order ----
// o[((cg*16+ks)*64 + l)*8 + j] = bf16(W[cg*16 + (l&15)][ks*32 + (l>>4)*8 + j])
__global__ void k_convert_wfrag(const float* __restrict__ w,
                                unsigned short* __restrict__ o) {
  int idx = blockIdx.x * 256 + threadIdx.x;   // 8192 threads
  int l   = idx & 63;
  int wks = idx >> 6;
  int cg  = wks >> 4, ks = wks & 15;
  int row = cg * 16 + (l & 15);
  int col = ks * 32 + (l >> 4) * 8;
  const float4* src = reinterpret_cast<const float4*>(w + row * ENCH + col);
  float4 v0 = src[0], v1 = src[1];
  short8 r;
  r[0] = (short)f2bf_rne(v0.x); r[1] = (short)f2bf_rne(v0.y);
  r[2] = (short)f2bf_rne(v0.z); r[3] = (short)f2bf_rne(v0.w);
  r[4] = (short)f2bf_rne(v1.x); r[5] = (short)f2bf_rne(v1.y);
  r[6] = (short)f2bf_rne(v1.z); r[7] = (short)f2bf_rne(v1.w);
  *reinterpret_cast<short8*>(o + (size_t)idx * 8) = r;
}

// ---- K0a: dec_proj[b][a] = sum_h dec[b,h] * W_dec[a,h]  (fp32) ----
__global__ void k_decproj(const float* __restrict__ dec,
                          const float* __restrict__ wdec,
                          float* __restrict__ out) {
  __shared__ float dh[ENCH];
  int b = blockIdx.x, tid = threadIdx.x;    // 128 threads
  for (int i = tid; i < ENCH; i += 128) dh[i] = dec[b * ENCH + i];
  __syncthreads();
  const float4* wr4 = reinterpret_cast<const float4*>(wdec + tid * ENCH);
  float acc = 0.f;
  for (int h4 = 0; h4 < ENCH / 4; ++h4) {
    float4 w4 = wr4[h4];
    acc += dh[h4 * 4 + 0] * w4.x + dh[h4 * 4 + 1] * w4.y +
           dh[h4 * 4 + 2] * w4.z + dh[h4 * 4 + 3] * w4.w;
  }
  out[b * ATTN_ + tid] = acc;
}

// ---- K1: persistent row-partitioned fused kernel.
// 256 blocks (1/CU) x 16 waves; W_enc frag-linear in LDS staged ONCE.
// Each wave: 16 rows end-to-end, enc read EXACTLY ONCE (kept as bf16 in
// af[16] regs); ctx reduced in-register via DPP butterflies. Zero block
// barriers after the W stage.
__global__ __launch_bounds__(1024, 4) void k_main(
    const float* __restrict__ enc,            // [B,T,512] fp32
    const unsigned short* __restrict__ wfrag, // frag-linear bf16 W_enc
    const float* __restrict__ decproj,        // [B,128] fp32
    const float* __restrict__ vw,             // [128] fp32
    float* __restrict__ scores_raw,           // [B,T] raw scores
    float* __restrict__ ctx_part,             // [B*128][512] per-wave partials
    float* __restrict__ ml_part)              // [B*128][2]
{
  const int tid  = threadIdx.x;
  const int lane = tid & 63;
  const int wid  = tid >> 6;       // 16 waves
  const int l15  = lane & 15;
  const int g    = lane >> 4;

  __shared__ unsigned short w_lds[ATTN_ * ENCH];  // 128 KiB, frag-linear

  // ---- stage W into LDS once (linear copy, coalesced, conflict-free) ----
#pragma unroll
  for (int r = 0; r < 8; ++r) {
    int i = r * 1024 + tid;
    reinterpret_cast<short8*>(w_lds)[i] = reinterpret_cast<const short8*>(wfrag)[i];
  }
  __syncthreads();   // the only block barrier

  for (int cid = blockIdx.x; cid < NCHUNK; cid += gridDim.x) {
    const int b = cid >> 3;
    const int s = cid & 7;
    const int row0 = s * CHUNK + wid * 16;
    const float* arow = enc + ((size_t)b * T_SZ + row0 + l15) * ENCH + g * 8;

    // ---- load 16 rows x K=512 as bf16 A-fragments (the ONLY enc read) ----
    short8 af[16];
#pragma unroll
    for (int ks = 0; ks < 16; ++ks) {
      float4 a0 = *reinterpret_cast<const float4*>(arow + ks * 32);
      float4 a1 = *reinterpret_cast<const float4*>(arow + ks * 32 + 4);
      af[ks] = pack8(a0, a1);
    }

    // ---- MFMA sweep: proj[16 rows][128 cols], B-frags from LDS ----
    f32x4 acc[8];
#pragma unroll
    for (int cg = 0; cg < 8; ++cg) acc[cg] = (f32x4){0.f, 0.f, 0.f, 0.f};
#pragma unroll
    for (int ks = 0; ks < 16; ++ks) {
      const char* wb = (const char*)w_lds + ks * 1024 + lane * 16;
#pragma unroll
      for (int cg = 0; cg < 8; ++cg) {
        short8 bf = *reinterpret_cast<const short8*>(wb + cg * 16384);
        acc[cg] = __builtin_amdgcn_mfma_f32_16x16x32_bf16(af[ks], bf, acc[cg], 0, 0, 0);
      }
    }

    // ---- scores: e = sum_col tanh(proj+dec)*v ; C layout row=4g+r, col=cg*16+l15
    float er[4];
    {
      float dv[8], vv[8];
#pragma unroll
      for (int cg = 0; cg < 8; ++cg) {
        dv[cg] = decproj[b * ATTN_ + cg * 16 + l15];
        vv[cg] = vw[cg * 16 + l15];
      }
#pragma unroll
      for (int r = 0; r < 4; ++r) {
        float e = 0.f;
#pragma unroll
        for (int cg = 0; cg < 8; ++cg)
          e += fast_tanh(acc[cg][r] + dv[cg]) * vv[cg];
        er[r] = sum16(e);          // all 16 lanes of group g get score[4g+r]
      }
    }
    if (l15 == 0) {
#pragma unroll
      for (int r = 0; r < 4; ++r)
        scores_raw[(size_t)b * T_SZ + row0 + g * 4 + r] = er[r];
    }

    // ---- wave-private softmax over its 16 rows (cross-g via 2 shfls) ----
    float mg = fmaxf(fmaxf(er[0], er[1]), fmaxf(er[2], er[3]));
    mg = fmaxf(mg, __shfl_xor(mg, 16));
    mg = fmaxf(mg, __shfl_xor(mg, 32));
    float x0 = __expf(er[0] - mg), x1 = __expf(er[1] - mg);
    float x2 = __expf(er[2] - mg), x3 = __expf(er[3] - mg);
    float xs = (x0 + x1) + (x2 + x3);
    xs += __shfl_xor(xs, 16);
    xs += __shfl_xor(xs, 32);
    const float l_run = xs;
    // p for MY row (t = l15): pick er[l15&3] from group l15>>2
    float sel = (l15 & 3) == 0 ? er[0]
              : (l15 & 3) == 1 ? er[1]
              : (l15 & 3) == 2 ? er[2] : er[3];
    float smine = __shfl(sel, ((l15 >> 2) << 4) | (l15 & 3));
    const float p_me = __expf(smine - mg);

    // ---- ctx from af (in-register): lane contributes its row, DPP-reduce ----
    float ctx8[8];
#pragma unroll
    for (int j = 0; j < 8; ++j) ctx8[j] = 0.f;
#pragma unroll
    for (int ks = 0; ks < 16; ++ks) {
      float c[8];
#pragma unroll
      for (int j = 0; j < 8; ++j)
        c[j] = p_me * bf2f((unsigned short)af[ks][j]);
#pragma unroll
      for (int j = 0; j < 8; ++j) c[j] = sum16(c[j]);
      if (l15 == ks) {
#pragma unroll
        for (int j = 0; j < 8; ++j) ctx8[j] = c[j];   // lane owns h=l15*32+g*8+j
      }
    }

    // ---- write per-wave partials (no in-block reduce; k_combine merges) ----
    const size_t widx = (size_t)b * 128 + s * 16 + wid;
    float* cp = ctx_part + widx * ENCH + l15 * 32 + g * 8;
    *reinterpret_cast<float4*>(cp)     = (float4){ctx8[0], ctx8[1], ctx8[2], ctx8[3]};
    *reinterpret_cast<float4*>(cp + 4) = (float4){ctx8[4], ctx8[5], ctx8[6], ctx8[7]};
    if (lane == 0) {
      ml_part[widx * 2 + 0] = mg;
      ml_part[widx * 2 + 1] = l_run;
    }
  }
}

// ---- K2: merge 128 per-wave partials per batch; normalize weights ----
__global__ void k_combine(const float* __restrict__ ctx_part,
                          const float* __restrict__ ml_part,
                          float* __restrict__ out_ctx,   // [B,512]
                          float* __restrict__ weights)   // [B,T], holds raw scores
{
  __shared__ float msh[128], lsh[128], fac[128];
  int b = blockIdx.x, tid = threadIdx.x;   // 256 threads
  if (tid < 128) {
    msh[tid] = ml_part[((size_t)b * 128 + tid) * 2 + 0];
    lsh[tid] = ml_part[((size_t)b * 128 + tid) * 2 + 1];
  }
  __syncthreads();
  float M = msh[0];
  for (int w = 1; w < 128; ++w) M = fmaxf(M, msh[w]);
  if (tid < 128) fac[tid] = __expf(msh[tid] - M);
  __syncthreads();
  float L = 0.f;
  for (int w = 0; w < 128; ++w) L += fac[w] * lsh[w];
  float Linv = 1.f / L;
  for (int h = tid; h < ENCH; h += 256) {
    float a = 0.f;
    for (int w = 0; w < 128; ++w)
      a += fac[w] * ctx_part[((size_t)b * 128 + w) * ENCH + h];
    out_ctx[b * ENCH + h] = a * Linv;
  }
  for (int t = tid; t < T_SZ; t += 256) {
    float raw = weights[(size_t)b * T_SZ + t];
    weights[(size_t)b * T_SZ + t] = __expf(raw - M) * Linv;
  }
}

extern "C" void kernel_launch(void* const* d_in, const int* in_sizes, int n_in,
                              void* d_out, int out_size, void* d_ws, size_t ws_size,
                              hipStream_t stream) {
  const float* enc  = (const float*)d_in[0];
  const float* dec  = (const float*)d_in[1];
  const float* wenc = (const float*)d_in[2];
  const float* wdec = (const float*)d_in[3];
  const float* vw   = (const float*)d_in[4];

  float* out     = (float*)d_out;
  float* out_ctx = out;                       // [B,512]
  float* out_w   = out + B_SZ * ENCH;         // [B,T] (raw scores, then weights)

  char* ws = (char*)d_ws;
  unsigned short* wfrag = (unsigned short*)ws;                      // 131072 B
  float* decproj  = (float*)(ws + 131072);                          // 65536 B
  float* ml_part  = (float*)(ws + 131072 + 65536);                  // 131072 B
  float* ctx_part = (float*)(ws + 131072 + 65536 + 131072);         // 32 MiB

  hipLaunchKernelGGL(k_convert_wfrag, dim3(32), dim3(256), 0, stream, wenc, wfrag);
  hipLaunchKernelGGL(k_decproj, dim3(B_SZ), dim3(128), 0, stream, dec, wdec, decproj);
  hipLaunchKernelGGL(k_main, dim3(256), dim3(1024), 0, stream,
                     enc, wfrag, decproj, vw, out_w, ctx_part, ml_part);
  hipLaunchKernelGGL(k_combine, dim3(B_SZ), dim3(256), 0, stream,
                     ctx_part, ml_part, out_ctx, out_w);
}